// Round 7
// baseline (111.876 us; speedup 1.0000x reference)
//
#include <hip/hip_runtime.h>

#define N_TOK    32768
#define NEMBED   1024
#define SCALE    32.0f   // sqrt(1024)
#define NTHREADS 256     // 4 waves per block

// static grid partition (4 blocks/CU resident, 1024 = one generation)
#define G0 152
#define G1 288    // %4 == 0  (cs slices)
#define G2 520    // %4 == 0
#define G3 64     // %4 == 0
#define GRID (G0 + G1 + G2 + G3)   // 1024

__device__ __forceinline__ int bucket_of(int idx) {
    return (idx < 20000) ? 0 : (idx < 40000) ? 1 : (idx < 200000) ? 2 : 3;
}

// ---------------- classify + compact tokens into per-bucket lists ----------------
__global__ void classify_kernel(const int* __restrict__ x,
                                int* __restrict__ cnt,      // [4]
                                int* __restrict__ lists) {  // [4][N_TOK]
    __shared__ int s_cnt[4], s_base[4];
    int tid = threadIdx.x;
    if (tid < 4) s_cnt[tid] = 0;
    __syncthreads();
    int t = blockIdx.x * blockDim.x + tid;
    int b = 0, p = 0;
    if (t < N_TOK) {
        b = bucket_of(x[t]);
        p = atomicAdd(&s_cnt[b], 1);
    }
    __syncthreads();
    if (tid < 4) s_base[tid] = atomicAdd(&cnt[tid], s_cnt[tid]);
    __syncthreads();
    if (t < N_TOK) lists[b * N_TOK + s_base[b] + p] = t;
}

// ---------------- bucket 0: row copy, chunks of 8 tokens ----------------
__device__ __forceinline__ void run_copy(const int* __restrict__ x,
                                         const float* __restrict__ table0,
                                         const int* __restrict__ list0,
                                         float* __restrict__ out,
                                         int n, int tile0, int stride,
                                         int* s_tok, int* s_row) {
    int ntiles = (n + 7) / 8;
    int tid = threadIdx.x;
    const float4* t4 = (const float4*)table0;
    float4* o4 = (float4*)out;
    #pragma unroll 1
    for (int t = tile0; t < ntiles; t += stride) {
        if (tid < 8) {
            int i = t * 8 + tid;
            int tok = (i < n) ? list0[i] : -1;
            s_tok[tid] = tok;
            s_row[tid] = (tok >= 0) ? x[tok] : -1;
        }
        __syncthreads();
        #pragma unroll
        for (int q = 0; q < 8; ++q) {
            int f4 = q * NTHREADS + tid;          // 0..2047 = 8 tok x 256 f4
            int tt = f4 >> 8, c4 = f4 & 255;
            int tok = s_tok[tt];
            if (tok >= 0) {
                float4 v = t4[(size_t)s_row[tt] * 256 + c4];
                v.x *= SCALE; v.y *= SCALE; v.z *= SCALE; v.w *= SCALE;
                o4[(size_t)tok * 256 + c4] = v;
            }
        }
        __syncthreads();
    }
}

// ---------------- buckets 1..3: P from global(L2) + E in LDS (dbuf, 2-ahead ids) ----
// chunk = 4*TW tokens; wave tg owns tokens [TW*tg, TW*tg+TW), cols [cs*256, +256).
template <int D, int TW>
__device__ __forceinline__ void run_proj(const int* __restrict__ x,
                                         const float* __restrict__ table,
                                         const float* __restrict__ proj,
                                         const int* __restrict__ list_b,
                                         float* __restrict__ out,
                                         int n, int start,
                                         int cs, int chunk0, int cstride,
                                         float4* __restrict__ E4,   // [2][CH*D4]
                                         int* __restrict__ s_tok,   // [2][CH]
                                         int* __restrict__ s_row) { // [2][CH]
    constexpr int CH   = 4 * TW;        // tokens per chunk
    constexpr int D4   = D / 4;
    constexpr int NF4E = CH * D4;       // f4 per E buffer (1024 / 512 / 128)
    constexpr int STG  = (NF4E + NTHREADS - 1) / NTHREADS;

    int tid = threadIdx.x;
    int nchunk = (n + CH - 1) / CH;
    int myN = (chunk0 < nchunk) ? ((nchunk - 1 - chunk0) / cstride + 1) : 0;
    if (myN == 0) return;

    const float4* tb4 = (const float4*)table;
    const float4* pp  = (const float4*)proj;
    int lane = tid & 63, tg = tid >> 6;
    int pcol = cs * 64 + lane;                    // f4 col index into proj row

    // ---- prologue: ids(0), ids(1)
    if (tid < CH) {
        int i = chunk0 * CH + tid;
        int tok = (i < n) ? list_b[i] : -1;
        s_tok[tid] = tok;
        s_row[tid] = (tok >= 0) ? (x[tok] - start) : -1;
        if (myN > 1) {
            int i1 = (chunk0 + cstride) * CH + tid;
            int tok1 = (i1 < n) ? list_b[i1] : -1;
            s_tok[CH + tid] = tok1;
            s_row[CH + tid] = (tok1 >= 0) ? (x[tok1] - start) : -1;
        }
    }
    __syncthreads();
    // ---- E(0) -> buf0
    #pragma unroll
    for (int q = 0; q < STG; ++q) {
        int f4 = q * NTHREADS + tid;
        if (f4 < NF4E) {
            int row = s_row[f4 / D4];
            E4[f4] = (row >= 0) ? tb4[(size_t)row * D4 + (f4 % D4)]
                                : make_float4(0.f, 0.f, 0.f, 0.f);
        }
    }
    __syncthreads();

    #pragma unroll 1
    for (int ti = 0; ti < myN; ++ti) {
        int sl = ti & 1;
        bool hn = (ti + 1 < myN), h2 = (ti + 2 < myN);

        // stage E(ti+1) -> regs (issue early; overlaps compute)
        float4 st[STG];
        #pragma unroll
        for (int q = 0; q < STG; ++q) st[q] = make_float4(0.f, 0.f, 0.f, 0.f);
        if (hn) {
            #pragma unroll
            for (int q = 0; q < STG; ++q) {
                int f4 = q * NTHREADS + tid;
                if (f4 < NF4E) {
                    int row = s_row[(sl ^ 1) * CH + f4 / D4];
                    if (row >= 0) st[q] = tb4[(size_t)row * D4 + (f4 % D4)];
                }
            }
        }
        // list(ti+2)
        int lreg = -1;
        if (h2 && tid < CH) {
            int i2 = (chunk0 + (ti + 2) * cstride) * CH + tid;
            lreg = (i2 < n) ? list_b[i2] : -1;
        }

        // ---- compute chunk ti: P from global with 1-deep prefetch, E broadcast from LDS
        const float4* Ec = E4 + sl * NF4E;
        float4 acc[TW];
        #pragma unroll
        for (int j = 0; j < TW; j++) acc[j] = make_float4(0.f, 0.f, 0.f, 0.f);

        float4 pc0 = pp[(size_t)0 * 256 + pcol];
        float4 pc1 = pp[(size_t)1 * 256 + pcol];
        float4 pc2 = pp[(size_t)2 * 256 + pcol];
        float4 pc3 = pp[(size_t)3 * 256 + pcol];
        #pragma unroll 1
        for (int kg = 0; kg < D4; ++kg) {
            int nk = (kg + 1 < D4) ? kg + 1 : kg;
            float4 q0 = pp[(size_t)(4 * nk + 0) * 256 + pcol];
            float4 q1 = pp[(size_t)(4 * nk + 1) * 256 + pcol];
            float4 q2 = pp[(size_t)(4 * nk + 2) * 256 + pcol];
            float4 q3 = pp[(size_t)(4 * nk + 3) * 256 + pcol];
            #pragma unroll
            for (int h = 0; h < TW / 4; ++h) {
                #pragma unroll
                for (int j = 0; j < 4; ++j) {
                    float4 e = Ec[(tg * TW + 4 * h + j) * D4 + kg];  // wave-uniform broadcast
                    float4& a = acc[4 * h + j];
                    a.x += e.x * pc0.x + e.y * pc1.x + e.z * pc2.x + e.w * pc3.x;
                    a.y += e.x * pc0.y + e.y * pc1.y + e.z * pc2.y + e.w * pc3.y;
                    a.z += e.x * pc0.z + e.y * pc1.z + e.z * pc2.z + e.w * pc3.z;
                    a.w += e.x * pc0.w + e.y * pc1.w + e.z * pc2.w + e.w * pc3.w;
                }
            }
            pc0 = q0; pc1 = q1; pc2 = q2; pc3 = q3;
        }

        #pragma unroll
        for (int j = 0; j < TW; j++) {
            int tok = s_tok[sl * CH + tg * TW + j];
            if (tok >= 0) {
                float4 v = acc[j];
                v.x *= SCALE; v.y *= SCALE; v.z *= SCALE; v.w *= SCALE;
                *(float4*)&out[(size_t)tok * NEMBED + cs * 256 + lane * 4] = v;
            }
        }

        // resolve ids(ti+2)
        int row2 = -1;
        if (h2 && tid < CH && lreg >= 0) row2 = x[lreg] - start;

        // commit E(ti+1) -> buf sl^1 (stale since previous barrier; safe pre-barrier)
        if (hn) {
            #pragma unroll
            for (int q = 0; q < STG; ++q) {
                int f4 = q * NTHREADS + tid;
                if (f4 < NF4E) E4[(sl ^ 1) * NF4E + f4] = st[q];
            }
        }
        __syncthreads();   // E-commit visible; all waves done with ids slot sl
        if (h2 && tid < CH) { s_tok[sl * CH + tid] = lreg; s_row[sl * CH + tid] = row2; }
        __syncthreads();   // ids(ti+2) visible
    }
}

// ---------------- fused kernel ----------------
__global__ __launch_bounds__(NTHREADS, 4)   // 4 waves/EU -> VGPR <= 128, 4 blocks/CU
void fused_embed_kernel(const int* __restrict__ x,
                        const float* __restrict__ t0, const float* __restrict__ t1,
                        const float* __restrict__ t2, const float* __restrict__ t3,
                        const float* __restrict__ p1, const float* __restrict__ p2,
                        const float* __restrict__ p3,
                        const int* __restrict__ cnt,
                        const int* __restrict__ lists,
                        float* __restrict__ out) {
    __shared__ __align__(16) float4 E4[2048];   // 32 KB: max E dbuf (b1: 2x1024 f4)
    __shared__ int s_tok[64], s_row[64];

    int bid = blockIdx.x;
    if (bid < G0) {
        run_copy(x, t0, lists, out, cnt[0], bid, G0, s_tok, s_row);
    } else if (bid < G0 + G1) {
        int lb = bid - G0;
        run_proj<256, 4>(x, t1, p1, lists + 1 * N_TOK, out, cnt[1], 20000,
                         lb & 3, lb >> 2, G1 / 4, E4, s_tok, s_row);
    } else if (bid < G0 + G1 + G2) {
        int lb = bid - (G0 + G1);
        run_proj<64, 8>(x, t2, p2, lists + 2 * N_TOK, out, cnt[2], 40000,
                        lb & 3, lb >> 2, G2 / 4, E4, s_tok, s_row);
    } else {
        int lb = bid - (G0 + G1 + G2);
        run_proj<16, 8>(x, t3, p3, lists + 3 * N_TOK, out, cnt[3], 200000,
                        lb & 3, lb >> 2, G3 / 4, E4, s_tok, s_row);
    }
}

extern "C" void kernel_launch(void* const* d_in, const int* in_sizes, int n_in,
                              void* d_out, int out_size, void* d_ws, size_t ws_size,
                              hipStream_t stream) {
    const int*   x  = (const int*)d_in[0];
    const float* t0 = (const float*)d_in[1];
    const float* t1 = (const float*)d_in[2];
    const float* t2 = (const float*)d_in[3];
    const float* t3 = (const float*)d_in[4];
    const float* p1 = (const float*)d_in[5];
    const float* p2 = (const float*)d_in[6];
    const float* p3 = (const float*)d_in[7];
    float* out = (float*)d_out;

    int* cnt   = (int*)d_ws;
    int* lists = cnt + 64;

    hipMemsetAsync(d_ws, 0, 64 * sizeof(int), stream);
    classify_kernel<<<N_TOK / 256, 256, 0, stream>>>(x, cnt, lists);

    fused_embed_kernel<<<GRID, NTHREADS, 0, stream>>>(x, t0, t1, t2, t3, p1, p2, p3,
                                                      cnt, lists, out);
}